// Round 3
// baseline (2588.641 us; speedup 1.0000x reference)
//
#include <hip/hip_runtime.h>
#include <stdint.h>

#define BATCH 512
#define D_IN  2048
#define D_MCB 16000
#define N_OUT 3000

typedef __bf16 bf16x8 __attribute__((ext_vector_type(8)));
typedef __bf16 bf16x4 __attribute__((ext_vector_type(4)));
typedef float  f32x4  __attribute__((ext_vector_type(4)));
typedef float  f32x2  __attribute__((ext_vector_type(2)));

// Native LDS float atomic add (fire-and-forget). addr = 32-bit LDS byte addr.
__device__ __forceinline__ void lds_fadd(unsigned addr, float v) {
    asm volatile("ds_add_f32 %0, %1" :: "v"(addr), "v"(v) : "memory");
}

// Async global->LDS, 16 bytes per lane (linear dest: base + lane*16).
__device__ __forceinline__ void gload16(const void* g, void* l) {
    __builtin_amdgcn_global_load_lds(
        (const __attribute__((address_space(1))) unsigned*)g,
        (__attribute__((address_space(3))) unsigned*)l,
        16, 0, 0);
}

// ---------------------------------------------------------------------------
// Kernel 1: count-sketch + circular convolution, GATHER with bf16 p2 table.
// R6 rewrite of phase 4: the R3 single-pass body measured ~405 VALU/iter vs
// ~175 hand-counted (reg-pressure bloat at 104 VGPR: zacc[64]+w[36]). Fix:
//   (a) two 32-k half-passes over i -> 16 float2 acc + 5 chunks = ~70 live.
//   (b) v_pk_fma_f32 (full-rate packed fp32): 2 unpack + 1 pk_fma per elem
//       PAIR = 3 VALU / 2 elems (was 4). Exact: bf16 lo = bits<<16,
//       hi = bits & 0xffff0000; pk_fma is fused fp32, same numerics as fmac.
// Bank conflicts (2.887e8 = 7.65/b128) are the structural 8-cycle wave64
// b128 serialization -- swizzle already bank-optimal, leave as-is.
// ---------------------------------------------------------------------------
__global__ __launch_bounds__(256, 2) void mcb_conv_kernel(
    const float* __restrict__ x0, const float* __restrict__ x1,
    const float* __restrict__ s1, const float* __restrict__ s2,
    const int* __restrict__ h1, const int* __restrict__ h2,
    __bf16* __restrict__ zb)
{
    __shared__ __align__(16) char smem[81920];
    unsigned short* p2x  = (unsigned short*)smem;          // [32768] bf16 bits
    float*          p2f  = (float*)smem;                   // [16000] fp32 overlay
    float2*         idata = (float2*)(smem + 65536);       // [2048] (a1, s bits)

    const int b    = blockIdx.x;
    const int t    = threadIdx.x;
    const int lane = t & 63;
    const int wave = t >> 6;

    // --- phase 1: zero fp32 p2, stage idata ---
    for (int k = t; k < D_MCB; k += 256) p2f[k] = 0.0f;
    for (int i = t; i < D_IN; i += 256) {
        float a1 = s1[i] * x0[b * D_IN + i];
        int   s  = D_MCB - h1[i];                 // in [1, 16000]
        idata[i] = make_float2(a1, __int_as_float(s));
    }
    __syncthreads();

    // --- phase 2: scatter p2 (fp32, plain layout, tiny: 2048 atomics) ---
    for (int j = t; j < D_IN; j += 256) {
        float a2 = s2[j] * x1[b * D_IN + j];
        unsigned addr = (unsigned)(uintptr_t)&p2f[h2[j]];
        lds_fadd(addr, a2);
    }
    __syncthreads();

    // --- phase 3: fp32 p2 -> bf16 p2x, replicated to 32768 elems,
    //     XOR-swizzled at 16 B chunks: phys = c ^ ((c>>3)&7). Register-staged
    //     (read all, barrier, write) since p2x overlays p2f. ---
    bf16x8 stage[16];
#pragma unroll
    for (int m = 0; m < 16; ++m) {
        int c  = t + 256 * m;                     // chunk in [0,4096)
        int e8 = c << 3;                          // elem base, [0,32768)
        if (e8 >= 2 * D_MCB) e8 -= 2 * D_MCB;
        else if (e8 >= D_MCB) e8 -= D_MCB;
        f32x4 lo = *(const f32x4*)(p2f + e8);
        f32x4 hi = *(const f32x4*)(p2f + e8 + 4);
        bf16x8 o;
#pragma unroll
        for (int q = 0; q < 4; ++q) { o[q] = (__bf16)lo[q]; o[q + 4] = (__bf16)hi[q]; }
        stage[m] = o;
    }
    __syncthreads();
#pragma unroll
    for (int m = 0; m < 16; ++m) {
        int c  = t + 256 * m;
        int pc = c ^ ((c >> 3) & 7);
        *(bf16x8*)(p2x + pc * 8) = stage[m];
    }
    __syncthreads();

    // --- phase 4: gather, two 32-k half-passes. Lane owns k in [k0,k0+64),
    //     wave w covers [4000w, 4000w+4096) (overlap masked at store). ---
    const int k0   = wave * 4000 + (lane << 6);   // multiple of 8
    const int klim = wave * 4000 + 4000;

    // Per pair m (k = k0h+2m, k0h+2m+1), elems e = 2m+D, 2m+1+D of window:
    //   D even: both in dword m+D/2 (lo<<16, hi&mask)
    //   D odd : lo = dword m+(D-1)/2 hi-half, hi = dword m+(D+1)/2 lo-half
#define PKF(D)                                                            \
    {                                                                     \
        const unsigned* wd = (const unsigned*)w;                          \
        _Pragma("unroll")                                                 \
        for (int m = 0; m < 16; ++m) {                                    \
            unsigned blo, bhi;                                            \
            if ((D) & 1) {                                                \
                blo = wd[m + ((D) - 1) / 2] & 0xffff0000u;                \
                bhi = wd[m + ((D) + 1) / 2] << 16;                        \
            } else {                                                      \
                unsigned dwv = wd[m + (D) / 2];                           \
                blo = dwv << 16;                                          \
                bhi = dwv & 0xffff0000u;                                  \
            }                                                             \
            f32x2 pr;                                                     \
            pr[0] = __uint_as_float(blo);                                 \
            pr[1] = __uint_as_float(bhi);                                 \
            asm("v_pk_fma_f32 %0, %1, %2, %0"                             \
                : "+v"(zacc2[m]) : "v"(ab), "v"(pr));                     \
        }                                                                 \
    }

    for (int h = 0; h < 2; ++h) {
        const int k0h = k0 + 32 * h;
        const int K8h = k0h >> 3;

        f32x2 zacc2[16];
#pragma unroll
        for (int m = 0; m < 16; ++m) { zacc2[m][0] = 0.f; zacc2[m][1] = 0.f; }

        float2 jd = idata[0];
        for (int i = 0; i < D_IN; ++i) {
            float a1 = jd.x;
            int   s  = __float_as_int(jd.y);
            jd = idata[(i + 1) & (D_IN - 1)];      // broadcast prefetch

            const int c0 = K8h + (s >> 3);         // window chunk base
            const int dl = s & 7;                  // wave-uniform delta

            uint4 w[5];                            // 40 elems >= 32+7+1
#pragma unroll
            for (int tt = 0; tt < 5; ++tt) {
                int c = c0 + tt;
                w[tt] = *(const uint4*)(p2x + (c ^ ((c >> 3) & 7)) * 8);
            }

            f32x2 ab; ab[0] = a1; ab[1] = a1;

            switch (dl) {
                case 0: PKF(0) break;
                case 1: PKF(1) break;
                case 2: PKF(2) break;
                case 3: PKF(3) break;
                case 4: PKF(4) break;
                case 5: PKF(5) break;
                case 6: PKF(6) break;
                default: PKF(7) break;
            }
        }

        // store 32 elems of this half (all bounds % 8 == 0)
#pragma unroll
        for (int g = 0; g < 4; ++g) {
            int kg = k0h + g * 8;
            if (kg < klim) {
                bf16x8 o;
#pragma unroll
                for (int e = 0; e < 8; ++e)
                    o[e] = (__bf16)zacc2[(g * 8 + e) >> 1][(g * 8 + e) & 1];
                *(bf16x8*)(zb + (size_t)b * D_MCB + kg) = o;
            }
        }
    }
#undef PKF
}

// ---------------------------------------------------------------------------
// Kernel 1.5: W fp32 -> bf16 pre-convert (one pass).
// ---------------------------------------------------------------------------
__global__ __launch_bounds__(256) void wconv_kernel(
    const float* __restrict__ W, __bf16* __restrict__ Wb)
{
    size_t i = ((size_t)blockIdx.x * 256 + threadIdx.x) * 4;
    f32x4 w = *(const f32x4*)(W + i);
    bf16x4 o;
#pragma unroll
    for (int q = 0; q < 4; ++q) o[q] = (__bf16)w[q];
    *(bf16x4*)(Wb + i) = o;
}

// ---------------------------------------------------------------------------
// Kernel 2: LDS-staged bf16 GEMM. R6 reshape: BM=64 x BN=128, BK=64,
// grid = 24 n-blocks x 8 m-blocks = 192 (1D, XCD-swizzled so the 8 m-blocks
// sharing one Wb panel land on the same XCD -> panel K-slices served by L2).
// 4 waves (2M x 2N), double-buffered LDS (48 KB), global_load_lds width=16,
// XOR chunk swizzle phys = c ^ (row&7). out = relu(z @ Wb^T + bias).
// ---------------------------------------------------------------------------
__global__ __launch_bounds__(256) void mcb_gemm_tiled_kernel(
    const __bf16* __restrict__ zbm, const __bf16* __restrict__ Wb,
    const float* __restrict__ bias, float* __restrict__ out)
{
    // LDS: A buf 8192 B (64 rows), B buf 16384 B (128 rows), x2 = 49152 B
    __shared__ __align__(16) char tile[49152];

    const int t    = threadIdx.x;
    const int lane = t & 63;
    const int wave = t >> 6;
    const int llo  = lane & 15;
    const int lhi  = lane >> 4;
    const int wm   = wave >> 1;            // 0..1 : M strip of 32
    const int wn   = wave & 1;             // 0..1 : N strip of 64

    // XCD swizzle decode: f = r + 8*(y + 8*a); x = 8a + r (n-block), y (m-block).
    // Sharers of a Wb panel (same x, y=0..7) have equal f%8 -> same XCD.
    const int f  = blockIdx.x;
    const int r  = f & 7;
    const int g  = f >> 3;
    const int yb = g & 7;
    const int xb = (g >> 3) * 8 + r;

    const int m0 = yb * 64;
    const int n0 = xb * 128;

    // --- staging: linear LDS dest, inverse-swizzled global source ---
    const __bf16* asrc[2];
    const __bf16* bsrc[4];
    int aoff[2], boff[4];
#pragma unroll
    for (int p = 0; p < 2; ++p) {
        int fb    = (p * 256 + t) * 16;    // byte offset in 8 KB A tile
        int row   = fb >> 7;               // 0..63 (128 B per row = 64 bf16)
        int physc = (fb >> 4) & 7;
        int logc  = physc ^ (row & 7);
        asrc[p] = zbm + (size_t)(m0 + row) * D_MCB + logc * 8;
        aoff[p] = fb;
    }
#pragma unroll
    for (int p = 0; p < 4; ++p) {
        int fb    = (p * 256 + t) * 16;    // byte offset in 16 KB B tile
        int row   = fb >> 7;               // 0..127
        int wrow  = n0 + row;
        if (wrow > N_OUT - 1) wrow = N_OUT - 1;   // clamp pad rows (masked at store)
        int physc = (fb >> 4) & 7;
        int logc  = physc ^ (row & 7);
        bsrc[p] = Wb + (size_t)wrow * D_MCB + logc * 8;
        boff[p] = 8192 + fb;
    }

#define STAGE(bufsel, kt)                                                  \
    {                                                                      \
        const int bo_ = (bufsel) * 24576;                                  \
        const int ke_ = (kt) * 64;                                         \
        _Pragma("unroll")                                                  \
        for (int p = 0; p < 2; ++p) gload16(asrc[p] + ke_, tile + bo_ + aoff[p]); \
        _Pragma("unroll")                                                  \
        for (int p = 0; p < 4; ++p) gload16(bsrc[p] + ke_, tile + bo_ + boff[p]); \
    }

    // --- fragment read offsets (swizzled) ---
    int ard[2][2], brd[4][2];
#pragma unroll
    for (int am = 0; am < 2; ++am)
#pragma unroll
        for (int ks = 0; ks < 2; ++ks) {
            int row = wm * 32 + am * 16 + llo;
            int c   = lhi + ks * 4;
            ard[am][ks] = row * 128 + (c ^ (row & 7)) * 16;
        }
#pragma unroll
    for (int bn = 0; bn < 4; ++bn)
#pragma unroll
        for (int ks = 0; ks < 2; ++ks) {
            int row = wn * 64 + bn * 16 + llo;
            int c   = lhi + ks * 4;
            brd[bn][ks] = 8192 + row * 128 + (c ^ (row & 7)) * 16;
        }

    f32x4 acc[2][4] = {};

    STAGE(0, 0);
    __syncthreads();

    int buf = 0;
    for (int kt = 0; kt < 250; ++kt) {
        if (kt + 1 < 250) STAGE(buf ^ 1, kt + 1);

        const char* base = tile + buf * 24576;
        bf16x8 a[2][2], bfr[4][2];
#pragma unroll
        for (int am = 0; am < 2; ++am)
#pragma unroll
            for (int ks = 0; ks < 2; ++ks)
                a[am][ks] = *(const bf16x8*)(base + ard[am][ks]);
#pragma unroll
        for (int bn = 0; bn < 4; ++bn)
#pragma unroll
            for (int ks = 0; ks < 2; ++ks)
                bfr[bn][ks] = *(const bf16x8*)(base + brd[bn][ks]);

#pragma unroll
        for (int ks = 0; ks < 2; ++ks)
#pragma unroll
            for (int am = 0; am < 2; ++am)
#pragma unroll
                for (int bn = 0; bn < 4; ++bn)
                    acc[am][bn] = __builtin_amdgcn_mfma_f32_16x16x32_bf16(
                        a[am][ks], bfr[bn][ks], acc[am][bn], 0, 0, 0);

        __syncthreads();
        buf ^= 1;
    }
#undef STAGE

    // --- epilogue: C/D layout col=lane&15, row=(lane>>4)*4+r ---
#pragma unroll
    for (int bn = 0; bn < 4; ++bn) {
        int col = n0 + wn * 64 + bn * 16 + llo;
        if (col < N_OUT) {
            float bv = bias[col];
#pragma unroll
            for (int am = 0; am < 2; ++am) {
                int rbase = m0 + wm * 32 + am * 16 + lhi * 4;
#pragma unroll
                for (int rr = 0; rr < 4; ++rr) {
                    float v = acc[am][bn][rr] + bv;
                    out[(size_t)(rbase + rr) * N_OUT + col] = v > 0.0f ? v : 0.0f;
                }
            }
        }
    }
}

// ---------------------------------------------------------------------------
// Kernel 2 (fallback): W stays fp32, converted in-register (no workspace).
// ---------------------------------------------------------------------------
__global__ __launch_bounds__(256) void mcb_gemm_f32_kernel(
    const __bf16* __restrict__ zbm, const float* __restrict__ W,
    const float* __restrict__ bias, float* __restrict__ out)
{
    const int lane = threadIdx.x & 63;
    const int wave = threadIdx.x >> 6;
    const int wm = wave >> 1;
    const int wn = wave & 1;
    const int llo = lane & 15;
    const int lhi = lane >> 4;

    const int m0 = blockIdx.y * 64 + wm * 32;
    const int n0 = blockIdx.x * 64 + wn * 32;

    f32x4 acc[2][2] = {};

    const int arow0 = m0 + llo;
    const int bcol0 = n0 + llo;
    const int kk = lhi * 8;

    const __bf16* aptr0 = zbm + (size_t)arow0 * D_MCB + kk;
    const __bf16* aptr1 = aptr0 + (size_t)16 * D_MCB;
    const float*  bptr0 = W + (size_t)bcol0 * D_MCB + kk;
    const float*  bptr1 = bptr0 + (size_t)16 * D_MCB;
    const bool bok0 = (bcol0 < N_OUT);
    const bool bok1 = (bcol0 + 16 < N_OUT);

    for (int k = 0; k < D_MCB; k += 32) {
        bf16x8 a0 = *(const bf16x8*)(aptr0 + k);
        bf16x8 a1 = *(const bf16x8*)(aptr1 + k);

        bf16x8 b0 = {}, b1 = {};
        if (bok0) {
            f32x4 w0 = *(const f32x4*)(bptr0 + k);
            f32x4 w1 = *(const f32x4*)(bptr0 + k + 4);
#pragma unroll
            for (int q = 0; q < 4; ++q) { b0[q] = (__bf16)w0[q]; b0[q + 4] = (__bf16)w1[q]; }
        }
        if (bok1) {
            f32x4 w0 = *(const f32x4*)(bptr1 + k);
            f32x4 w1 = *(const f32x4*)(bptr1 + k + 4);
#pragma unroll
            for (int q = 0; q < 4; ++q) { b1[q] = (__bf16)w0[q]; b1[q + 4] = (__bf16)w1[q]; }
        }

        acc[0][0] = __builtin_amdgcn_mfma_f32_16x16x32_bf16(a0, b0, acc[0][0], 0, 0, 0);
        acc[0][1] = __builtin_amdgcn_mfma_f32_16x16x32_bf16(a0, b1, acc[0][1], 0, 0, 0);
        acc[1][0] = __builtin_amdgcn_mfma_f32_16x16x32_bf16(a1, b0, acc[1][0], 0, 0, 0);
        acc[1][1] = __builtin_amdgcn_mfma_f32_16x16x32_bf16(a1, b1, acc[1][1], 0, 0, 0);
    }

#pragma unroll
    for (int bn = 0; bn < 2; ++bn) {
        int col = bcol0 + bn * 16;
        if (col >= N_OUT) continue;
        float bv = bias[col];
#pragma unroll
        for (int am = 0; am < 2; ++am) {
            int rbase = m0 + am * 16 + lhi * 4;
#pragma unroll
            for (int rr = 0; rr < 4; ++rr) {
                float v = acc[am][bn][rr] + bv;
                out[(size_t)(rbase + rr) * N_OUT + col] = v > 0.0f ? v : 0.0f;
            }
        }
    }
}

extern "C" void kernel_launch(void* const* d_in, const int* in_sizes, int n_in,
                              void* d_out, int out_size, void* d_ws, size_t ws_size,
                              hipStream_t stream) {
    // setup_inputs() order: x0, x1, s1, s2, W, b, h1, h2
    const float* x0   = (const float*)d_in[0];
    const float* x1   = (const float*)d_in[1];
    const float* s1   = (const float*)d_in[2];
    const float* s2   = (const float*)d_in[3];
    const float* W    = (const float*)d_in[4];
    const float* bias = (const float*)d_in[5];
    const int*   h1   = (const int*)d_in[6];
    const int*   h2   = (const int*)d_in[7];
    float* out = (float*)d_out;

    const size_t zb_bytes = (size_t)BATCH * D_MCB * sizeof(__bf16);   // 16,384,000
    const size_t wb_bytes = (size_t)N_OUT * D_MCB * sizeof(__bf16);   // 96,000,000

    __bf16* zbm = (__bf16*)d_ws;

    mcb_conv_kernel<<<BATCH, 256, 0, stream>>>(x0, x1, s1, s2, h1, h2, zbm);

    if (ws_size >= zb_bytes + wb_bytes) {
        __bf16* Wb = (__bf16*)((char*)d_ws + zb_bytes);
        wconv_kernel<<<46875, 256, 0, stream>>>(W, Wb);
        mcb_gemm_tiled_kernel<<<192, 256, 0, stream>>>(zbm, Wb, bias, out);
    } else {
        mcb_gemm_f32_kernel<<<dim3(47, 8), 256, 0, stream>>>(zbm, W, bias, out);
    }
}

// Round 4
// 1582.665 us; speedup vs baseline: 1.6356x; 1.6356x over previous
//
#include <hip/hip_runtime.h>
#include <stdint.h>

#define BATCH 512
#define D_IN  2048
#define D_MCB 16000
#define N_OUT 3000

typedef __bf16 bf16x8 __attribute__((ext_vector_type(8)));
typedef __bf16 bf16x4 __attribute__((ext_vector_type(4)));
typedef float  f32x4  __attribute__((ext_vector_type(4)));

// Native LDS float atomic add (fire-and-forget). addr = 32-bit LDS byte addr.
__device__ __forceinline__ void lds_fadd(unsigned addr, float v) {
    asm volatile("ds_add_f32 %0, %1" :: "v"(addr), "v"(v) : "memory");
}

// Async global->LDS, 16 bytes per lane (linear dest: base + lane*16).
__device__ __forceinline__ void gload16(const void* g, void* l) {
    __builtin_amdgcn_global_load_lds(
        (const __attribute__((address_space(1))) unsigned*)g,
        (__attribute__((address_space(3))) unsigned*)l,
        16, 0, 0);
}

// ---------------------------------------------------------------------------
// Kernel 1: count-sketch + circular convolution, GATHER with bf16 p2 table.
//   z[b,k] = sum_i a1[b,i] * p2[b, (k + s_i) mod d],  s_i = d - h1[i]
// R7: R3 scalar body (pk_fma reverted: no packed-fp32 rate on gfx950, asm
// pair-movs cost extra — R6 measured +44% VALU cycles). NEW: i's bucketed by
// dl = s&7 -> the per-iter 8-way switch becomes 8 clean loops with
// compile-time dl. Theory: R3's 2.2x VALU bloat (405 vs ~183 instr/iter)
// is the per-iter 64-accumulator phi-merge across switch cases.
// dl==0 bucket needs only 8 chunks (saves ~12% DS on 1/8 of i's).
// Bank conflicts ~7.65/b128 are structural wave64 b128 serialization.
// ---------------------------------------------------------------------------
__global__ __launch_bounds__(256, 2) void mcb_conv_kernel(
    const float* __restrict__ x0, const float* __restrict__ x1,
    const float* __restrict__ s1, const float* __restrict__ s2,
    const int* __restrict__ h1, const int* __restrict__ h2,
    __bf16* __restrict__ zb)
{
    __shared__ __align__(16) char smem[81920];
    unsigned short* p2x   = (unsigned short*)smem;         // [32768] bf16 bits (ph4)
    float*          p2f   = (float*)smem;                  // [16000] fp32 overlay
    int*            cnt   = (int*)(smem + 64000);          // [8] bucket counts (pad region)
    int*            cur   = (int*)(smem + 64032);          // [8] cursors -> ends
    float2*         bdata = (float2*)(smem + 65536);       // [2048] bucketed (a1, s>>3)

    const int b    = blockIdx.x;
    const int t    = threadIdx.x;
    const int lane = t & 63;
    const int wave = t >> 6;

    // --- phase 1: zero p2f, zero counts, compute per-thread (a1, s) in regs ---
    if (t < 8) cnt[t] = 0;
    for (int k = t; k < D_MCB; k += 256) p2f[k] = 0.0f;

    float a1r[8];
    int   sr[8];
#pragma unroll
    for (int r = 0; r < 8; ++r) {
        int i  = t + 256 * r;
        a1r[r] = s1[i] * x0[(size_t)b * D_IN + i];
        sr[r]  = D_MCB - h1[i];                    // in [1, 16000]
    }
    __syncthreads();

    // --- phase 1b: bucket histogram + p2 scatter (overlapped) ---
#pragma unroll
    for (int r = 0; r < 8; ++r) atomicAdd(&cnt[sr[r] & 7], 1);
    for (int j = t; j < D_IN; j += 256) {
        float a2 = s2[j] * x1[(size_t)b * D_IN + j];
        lds_fadd((unsigned)(uintptr_t)&p2f[h2[j]], a2);
    }
    __syncthreads();

    if (t == 0) {
        int acc = 0;
        for (int d = 0; d < 8; ++d) { int c = cnt[d]; cur[d] = acc; acc += c; }
    }
    __syncthreads();

    // --- phase 1c: scatter (a1, s>>3) into bucketed order ---
#pragma unroll
    for (int r = 0; r < 8; ++r) {
        int slot = atomicAdd(&cur[sr[r] & 7], 1);
        bdata[slot] = make_float2(a1r[r], __int_as_float(sr[r] >> 3));
    }
    __syncthreads();
    // cur[d] is now the END index of bucket d; stash in regs before p2x
    // overwrites the pad region in phase 3.
    int ends[8];
#pragma unroll
    for (int d = 0; d < 8; ++d) ends[d] = cur[d];

    // --- phase 3: fp32 p2 -> bf16 p2x, replicated to 32768 elems,
    //     XOR-swizzled at 16 B chunks: phys = c ^ ((c>>3)&7). Register-staged
    //     (read all, barrier, write) since p2x overlays p2f. ---
    bf16x8 stage[16];
#pragma unroll
    for (int m = 0; m < 16; ++m) {
        int c  = t + 256 * m;                      // chunk in [0,4096)
        int e8 = c << 3;                           // elem base, [0,32768)
        if (e8 >= 2 * D_MCB) e8 -= 2 * D_MCB;
        else if (e8 >= D_MCB) e8 -= D_MCB;
        f32x4 lo = *(const f32x4*)(p2f + e8);
        f32x4 hi = *(const f32x4*)(p2f + e8 + 4);
        bf16x8 o;
#pragma unroll
        for (int q = 0; q < 4; ++q) { o[q] = (__bf16)lo[q]; o[q + 4] = (__bf16)hi[q]; }
        stage[m] = o;
    }
    __syncthreads();
#pragma unroll
    for (int m = 0; m < 16; ++m) {
        int c  = t + 256 * m;
        int pc = c ^ ((c >> 3) & 7);
        *(bf16x8*)(p2x + pc * 8) = stage[m];
    }
    __syncthreads();

    // --- phase 4: gather over bucketed i's. Lane owns k in [k0, k0+64),
    //     wave w covers [4000w, 4000w+4096) (overlap masked at store). ---
    const int k0 = wave * 4000 + (lane << 6);      // multiple of 8
    const int K8 = k0 >> 3;

    float zacc[64];
#pragma unroll
    for (int q = 0; q < 64; ++q) zacc[q] = 0.f;

    // Per i: load NC window chunks, then 64 x (unpack + fmac) with
    // compile-time delta D. bf16->f32: lo half = bits<<16, hi half =
    // bits & 0xffff0000 (both exact).
#define BUCKET(D, NC)                                                      \
    {                                                                      \
        const int end = __builtin_amdgcn_readfirstlane(ends[(D)]);         \
        for (; pos < end; ++pos) {                                         \
            float a1  = jd.x;                                              \
            int   csh = __float_as_int(jd.y);                              \
            jd = bdata[(pos + 1) & (D_IN - 1)];    /* broadcast prefetch */ \
            const int c0 = K8 + csh;                                       \
            uint4 w[9];                                                    \
            _Pragma("unroll")                                              \
            for (int tt = 0; tt < (NC); ++tt) {                            \
                int c = c0 + tt;                                           \
                w[tt] = *(const uint4*)(p2x + (c ^ ((c >> 3) & 7)) * 8);   \
            }                                                              \
            const unsigned* wd = (const unsigned*)w;                       \
            _Pragma("unroll")                                              \
            for (int q = 0; q < 64; ++q) {                                 \
                const int e = q + (D);                                     \
                unsigned dwv  = wd[e >> 1];                                \
                unsigned bits = (e & 1) ? (dwv & 0xffff0000u) : (dwv << 16); \
                zacc[q] += a1 * __uint_as_float(bits);                     \
            }                                                              \
        }                                                                  \
    }

    float2 jd = bdata[0];
    int pos = 0;
    BUCKET(0, 8)
    BUCKET(1, 9)
    BUCKET(2, 9)
    BUCKET(3, 9)
    BUCKET(4, 9)
    BUCKET(5, 9)
    BUCKET(6, 9)
    BUCKET(7, 9)
#undef BUCKET

    // --- store bf16 z, masking wave overlap (all bounds % 8 == 0) ---
    const int klim = wave * 4000 + 4000;
#pragma unroll
    for (int g = 0; g < 8; ++g) {
        int kg = k0 + g * 8;
        if (kg < klim) {
            bf16x8 o;
#pragma unroll
            for (int e = 0; e < 8; ++e) o[e] = (__bf16)zacc[g * 8 + e];
            *(bf16x8*)(zb + (size_t)b * D_MCB + kg) = o;
        }
    }
}

// ---------------------------------------------------------------------------
// Kernel 1.5: W fp32 -> bf16 pre-convert (one pass).
// ---------------------------------------------------------------------------
__global__ __launch_bounds__(256) void wconv_kernel(
    const float* __restrict__ W, __bf16* __restrict__ Wb)
{
    size_t i = ((size_t)blockIdx.x * 256 + threadIdx.x) * 4;
    f32x4 w = *(const f32x4*)(W + i);
    bf16x4 o;
#pragma unroll
    for (int q = 0; q < 4; ++q) o[q] = (__bf16)w[q];
    *(bf16x4*)(Wb + i) = o;
}

// ---------------------------------------------------------------------------
// Kernel 2: LDS-staged bf16 GEMM (kept from R6: saved ~100us vs R5 shape).
// BM=64 x BN=128, BK=64, grid = 192 1D XCD-swizzled (8 m-blocks sharing a
// Wb panel land on one XCD -> panel K-slices served by L2). 4 waves (2Mx2N),
// double-buffered LDS (48 KB), global_load_lds width=16, XOR chunk swizzle
// phys = c ^ (row&7). out = relu(z @ Wb^T + bias).
// ---------------------------------------------------------------------------
__global__ __launch_bounds__(256) void mcb_gemm_tiled_kernel(
    const __bf16* __restrict__ zbm, const __bf16* __restrict__ Wb,
    const float* __restrict__ bias, float* __restrict__ out)
{
    __shared__ __align__(16) char tile[49152];

    const int t    = threadIdx.x;
    const int lane = t & 63;
    const int wave = t >> 6;
    const int llo  = lane & 15;
    const int lhi  = lane >> 4;
    const int wm   = wave >> 1;            // 0..1 : M strip of 32
    const int wn   = wave & 1;             // 0..1 : N strip of 64

    // XCD swizzle decode: f = r + 8*(y + 8*a); x = 8a + r (n-block), y (m-block).
    const int f  = blockIdx.x;
    const int r  = f & 7;
    const int g  = f >> 3;
    const int yb = g & 7;
    const int xb = (g >> 3) * 8 + r;

    const int m0 = yb * 64;
    const int n0 = xb * 128;

    // --- staging: linear LDS dest, inverse-swizzled global source ---
    const __bf16* asrc[2];
    const __bf16* bsrc[4];
    int aoff[2], boff[4];
#pragma unroll
    for (int p = 0; p < 2; ++p) {
        int fb    = (p * 256 + t) * 16;    // byte offset in 8 KB A tile
        int row   = fb >> 7;               // 0..63 (128 B per row = 64 bf16)
        int physc = (fb >> 4) & 7;
        int logc  = physc ^ (row & 7);
        asrc[p] = zbm + (size_t)(m0 + row) * D_MCB + logc * 8;
        aoff[p] = fb;
    }
#pragma unroll
    for (int p = 0; p < 4; ++p) {
        int fb    = (p * 256 + t) * 16;    // byte offset in 16 KB B tile
        int row   = fb >> 7;               // 0..127
        int wrow  = n0 + row;
        if (wrow > N_OUT - 1) wrow = N_OUT - 1;   // clamp pad rows (masked at store)
        int physc = (fb >> 4) & 7;
        int logc  = physc ^ (row & 7);
        bsrc[p] = Wb + (size_t)wrow * D_MCB + logc * 8;
        boff[p] = 8192 + fb;
    }

#define STAGE(bufsel, kt)                                                  \
    {                                                                      \
        const int bo_ = (bufsel) * 24576;                                  \
        const int ke_ = (kt) * 64;                                         \
        _Pragma("unroll")                                                  \
        for (int p = 0; p < 2; ++p) gload16(asrc[p] + ke_, tile + bo_ + aoff[p]); \
        _Pragma("unroll")                                                  \
        for (int p = 0; p < 4; ++p) gload16(bsrc[p] + ke_, tile + bo_ + boff[p]); \
    }

    // --- fragment read offsets (swizzled) ---
    int ard[2][2], brd[4][2];
#pragma unroll
    for (int am = 0; am < 2; ++am)
#pragma unroll
        for (int ks = 0; ks < 2; ++ks) {
            int row = wm * 32 + am * 16 + llo;
            int c   = lhi + ks * 4;
            ard[am][ks] = row * 128 + (c ^ (row & 7)) * 16;
        }
#pragma unroll
    for (int bn = 0; bn < 4; ++bn)
#pragma unroll
        for (int ks = 0; ks < 2; ++ks) {
            int row = wn * 64 + bn * 16 + llo;
            int c   = lhi + ks * 4;
            brd[bn][ks] = 8192 + row * 128 + (c ^ (row & 7)) * 16;
        }

    f32x4 acc[2][4] = {};

    STAGE(0, 0);
    __syncthreads();

    int buf = 0;
    for (int kt = 0; kt < 250; ++kt) {
        if (kt + 1 < 250) STAGE(buf ^ 1, kt + 1);

        const char* base = tile + buf * 24576;
        bf16x8 a[2][2], bfr[4][2];
#pragma unroll
        for (int am = 0; am < 2; ++am)
#pragma unroll
            for (int ks = 0; ks < 2; ++ks)
                a[am][ks] = *(const bf16x8*)(base + ard[am][ks]);
#pragma unroll
        for (int bn = 0; bn < 4; ++bn)
#pragma unroll
            for (int ks = 0; ks < 2; ++ks)
                bfr[bn][ks] = *(const bf16x8*)(base + brd[bn][ks]);

#pragma unroll
        for (int ks = 0; ks < 2; ++ks)
#pragma unroll
            for (int am = 0; am < 2; ++am)
#pragma unroll
                for (int bn = 0; bn < 4; ++bn)
                    acc[am][bn] = __builtin_amdgcn_mfma_f32_16x16x32_bf16(
                        a[am][ks], bfr[bn][ks], acc[am][bn], 0, 0, 0);

        __syncthreads();
        buf ^= 1;
    }
#undef STAGE

    // --- epilogue: C/D layout col=lane&15, row=(lane>>4)*4+r ---
#pragma unroll
    for (int bn = 0; bn < 4; ++bn) {
        int col = n0 + wn * 64 + bn * 16 + llo;
        if (col < N_OUT) {
            float bv = bias[col];
#pragma unroll
            for (int am = 0; am < 2; ++am) {
                int rbase = m0 + wm * 32 + am * 16 + lhi * 4;
#pragma unroll
                for (int rr = 0; rr < 4; ++rr) {
                    float v = acc[am][bn][rr] + bv;
                    out[(size_t)(rbase + rr) * N_OUT + col] = v > 0.0f ? v : 0.0f;
                }
            }
        }
    }
}

// ---------------------------------------------------------------------------
// Kernel 2 (fallback): W stays fp32, converted in-register (no workspace).
// ---------------------------------------------------------------------------
__global__ __launch_bounds__(256) void mcb_gemm_f32_kernel(
    const __bf16* __restrict__ zbm, const float* __restrict__ W,
    const float* __restrict__ bias, float* __restrict__ out)
{
    const int lane = threadIdx.x & 63;
    const int wave = threadIdx.x >> 6;
    const int wm = wave >> 1;
    const int wn = wave & 1;
    const int llo = lane & 15;
    const int lhi = lane >> 4;

    const int m0 = blockIdx.y * 64 + wm * 32;
    const int n0 = blockIdx.x * 64 + wn * 32;

    f32x4 acc[2][2] = {};

    const int arow0 = m0 + llo;
    const int bcol0 = n0 + llo;
    const int kk = lhi * 8;

    const __bf16* aptr0 = zbm + (size_t)arow0 * D_MCB + kk;
    const __bf16* aptr1 = aptr0 + (size_t)16 * D_MCB;
    const float*  bptr0 = W + (size_t)bcol0 * D_MCB + kk;
    const float*  bptr1 = bptr0 + (size_t)16 * D_MCB;
    const bool bok0 = (bcol0 < N_OUT);
    const bool bok1 = (bcol0 + 16 < N_OUT);

    for (int k = 0; k < D_MCB; k += 32) {
        bf16x8 a0 = *(const bf16x8*)(aptr0 + k);
        bf16x8 a1 = *(const bf16x8*)(aptr1 + k);

        bf16x8 b0 = {}, b1 = {};
        if (bok0) {
            f32x4 w0 = *(const f32x4*)(bptr0 + k);
            f32x4 w1 = *(const f32x4*)(bptr0 + k + 4);
#pragma unroll
            for (int q = 0; q < 4; ++q) { b0[q] = (__bf16)w0[q]; b0[q + 4] = (__bf16)w1[q]; }
        }
        if (bok1) {
            f32x4 w0 = *(const f32x4*)(bptr1 + k);
            f32x4 w1 = *(const f32x4*)(bptr1 + k + 4);
#pragma unroll
            for (int q = 0; q < 4; ++q) { b1[q] = (__bf16)w0[q]; b1[q + 4] = (__bf16)w1[q]; }
        }

        acc[0][0] = __builtin_amdgcn_mfma_f32_16x16x32_bf16(a0, b0, acc[0][0], 0, 0, 0);
        acc[0][1] = __builtin_amdgcn_mfma_f32_16x16x32_bf16(a0, b1, acc[0][1], 0, 0, 0);
        acc[1][0] = __builtin_amdgcn_mfma_f32_16x16x32_bf16(a1, b0, acc[1][0], 0, 0, 0);
        acc[1][1] = __builtin_amdgcn_mfma_f32_16x16x32_bf16(a1, b1, acc[1][1], 0, 0, 0);
    }

#pragma unroll
    for (int bn = 0; bn < 2; ++bn) {
        int col = bcol0 + bn * 16;
        if (col >= N_OUT) continue;
        float bv = bias[col];
#pragma unroll
        for (int am = 0; am < 2; ++am) {
            int rbase = m0 + am * 16 + lhi * 4;
#pragma unroll
            for (int rr = 0; rr < 4; ++rr) {
                float v = acc[am][bn][rr] + bv;
                out[(size_t)(rbase + rr) * N_OUT + col] = v > 0.0f ? v : 0.0f;
            }
        }
    }
}

extern "C" void kernel_launch(void* const* d_in, const int* in_sizes, int n_in,
                              void* d_out, int out_size, void* d_ws, size_t ws_size,
                              hipStream_t stream) {
    // setup_inputs() order: x0, x1, s1, s2, W, b, h1, h2
    const float* x0   = (const float*)d_in[0];
    const float* x1   = (const float*)d_in[1];
    const float* s1   = (const float*)d_in[2];
    const float* s2   = (const float*)d_in[3];
    const float* W    = (const float*)d_in[4];
    const float* bias = (const float*)d_in[5];
    const int*   h1   = (const int*)d_in[6];
    const int*   h2   = (const int*)d_in[7];
    float* out = (float*)d_out;

    const size_t zb_bytes = (size_t)BATCH * D_MCB * sizeof(__bf16);   // 16,384,000
    const size_t wb_bytes = (size_t)N_OUT * D_MCB * sizeof(__bf16);   // 96,000,000

    __bf16* zbm = (__bf16*)d_ws;

    mcb_conv_kernel<<<BATCH, 256, 0, stream>>>(x0, x1, s1, s2, h1, h2, zbm);

    if (ws_size >= zb_bytes + wb_bytes) {
        __bf16* Wb = (__bf16*)((char*)d_ws + zb_bytes);
        wconv_kernel<<<46875, 256, 0, stream>>>(W, Wb);
        mcb_gemm_tiled_kernel<<<192, 256, 0, stream>>>(zbm, Wb, bias, out);
    } else {
        mcb_gemm_f32_kernel<<<dim3(47, 8), 256, 0, stream>>>(zbm, W, bias, out);
    }
}

// Round 5
// 1332.313 us; speedup vs baseline: 1.9430x; 1.1879x over previous
//
#include <hip/hip_runtime.h>
#include <stdint.h>

#define BATCH 512
#define D_IN  2048
#define D_MCB 16000
#define N_OUT 3000

typedef __bf16 bf16x8 __attribute__((ext_vector_type(8)));
typedef __bf16 bf16x4 __attribute__((ext_vector_type(4)));
typedef _Float16 f16x8 __attribute__((ext_vector_type(8)));
typedef float  f32x4  __attribute__((ext_vector_type(4)));

// Native LDS float atomic add (fire-and-forget). addr = 32-bit LDS byte addr.
__device__ __forceinline__ void lds_fadd(unsigned addr, float v) {
    asm volatile("ds_add_f32 %0, %1" :: "v"(addr), "v"(v) : "memory");
}

// Async global->LDS, 16 bytes per lane (linear dest: base + lane*16).
__device__ __forceinline__ void gload16(const void* g, void* l) {
    __builtin_amdgcn_global_load_lds(
        (const __attribute__((address_space(1))) unsigned*)g,
        (__attribute__((address_space(3))) unsigned*)l,
        16, 0, 0);
}

// ---------------------------------------------------------------------------
// Kernel 1: count-sketch + circular convolution, GATHER with f16 p2 table.
//   z[b,k] = sum_i a1[b,i] * p2[b, (k + s_i) mod d],  s_i = d - h1[i]
// R8: table switched bf16 -> f16 and the unpack+fmac pair replaced by ONE
// v_fma_mix_f32 per element (op_sel picks the f16 half, conversion free in
// the FMA). R7 measured ~312 VALU/iter with 128 of them unpack+fmac; mix
// cuts the floor to ~110/iter. f16 is SAFE here: |p2| < ~10 (count-sketch of
// N(0,1)), and f16 has more mantissa than bf16 -> accuracy improves.
// Buckets by dl = s&7 (R7, compile-time delta per loop) retained.
// Bank conflicts ~4.5/b128 are structural wave64 b128 serialization.
// ---------------------------------------------------------------------------
__global__ __launch_bounds__(256, 2) void mcb_conv_kernel(
    const float* __restrict__ x0, const float* __restrict__ x1,
    const float* __restrict__ s1, const float* __restrict__ s2,
    const int* __restrict__ h1, const int* __restrict__ h2,
    __bf16* __restrict__ zb)
{
    __shared__ __align__(16) char smem[81920];
    unsigned short* p2x   = (unsigned short*)smem;         // [32768] f16 bits (ph4)
    float*          p2f   = (float*)smem;                  // [16000] fp32 overlay
    int*            cnt   = (int*)(smem + 64000);          // [8] bucket counts (pad region)
    int*            cur   = (int*)(smem + 64032);          // [8] cursors -> ends
    float2*         bdata = (float2*)(smem + 65536);       // [2048] bucketed (a1, s>>3)

    const int b    = blockIdx.x;
    const int t    = threadIdx.x;
    const int lane = t & 63;
    const int wave = t >> 6;

    // --- phase 1: zero p2f, zero counts, compute per-thread (a1, s) in regs ---
    if (t < 8) cnt[t] = 0;
    for (int k = t; k < D_MCB; k += 256) p2f[k] = 0.0f;

    float a1r[8];
    int   sr[8];
#pragma unroll
    for (int r = 0; r < 8; ++r) {
        int i  = t + 256 * r;
        a1r[r] = s1[i] * x0[(size_t)b * D_IN + i];
        sr[r]  = D_MCB - h1[i];                    // in [1, 16000]
    }
    __syncthreads();

    // --- phase 1b: bucket histogram + p2 scatter (overlapped) ---
#pragma unroll
    for (int r = 0; r < 8; ++r) atomicAdd(&cnt[sr[r] & 7], 1);
    for (int j = t; j < D_IN; j += 256) {
        float a2 = s2[j] * x1[(size_t)b * D_IN + j];
        lds_fadd((unsigned)(uintptr_t)&p2f[h2[j]], a2);
    }
    __syncthreads();

    if (t == 0) {
        int acc = 0;
        for (int d = 0; d < 8; ++d) { int c = cnt[d]; cur[d] = acc; acc += c; }
    }
    __syncthreads();

    // --- phase 1c: scatter (a1, s>>3) into bucketed order ---
#pragma unroll
    for (int r = 0; r < 8; ++r) {
        int slot = atomicAdd(&cur[sr[r] & 7], 1);
        bdata[slot] = make_float2(a1r[r], __int_as_float(sr[r] >> 3));
    }
    __syncthreads();
    // cur[d] is now the END index of bucket d; stash in regs before p2x
    // overwrites the pad region in phase 3.
    int ends[8];
#pragma unroll
    for (int d = 0; d < 8; ++d) ends[d] = cur[d];

    // --- phase 3: fp32 p2 -> f16 p2x, replicated to 32768 elems,
    //     XOR-swizzled at 16 B chunks: phys = c ^ ((c>>3)&7). Register-staged
    //     (read all, barrier, write) since p2x overlays p2f. ---
    f16x8 stage[16];
#pragma unroll
    for (int m = 0; m < 16; ++m) {
        int c  = t + 256 * m;                      // chunk in [0,4096)
        int e8 = c << 3;                           // elem base, [0,32768)
        if (e8 >= 2 * D_MCB) e8 -= 2 * D_MCB;
        else if (e8 >= D_MCB) e8 -= D_MCB;
        f32x4 lo = *(const f32x4*)(p2f + e8);
        f32x4 hi = *(const f32x4*)(p2f + e8 + 4);
        f16x8 o;
#pragma unroll
        for (int q = 0; q < 4; ++q) { o[q] = (_Float16)lo[q]; o[q + 4] = (_Float16)hi[q]; }
        stage[m] = o;
    }
    __syncthreads();
#pragma unroll
    for (int m = 0; m < 16; ++m) {
        int c  = t + 256 * m;
        int pc = c ^ ((c >> 3) & 7);
        *(f16x8*)(p2x + pc * 8) = stage[m];
    }
    __syncthreads();

    // --- phase 4: gather over bucketed i's. Lane owns k in [k0, k0+64),
    //     wave w covers [4000w, 4000w+4096) (overlap masked at store). ---
    const int k0 = wave * 4000 + (lane << 6);      // multiple of 8
    const int K8 = k0 >> 3;

    float zacc[64];
#pragma unroll
    for (int q = 0; q < 64; ++q) zacc[q] = 0.f;

    // Per i: load NC window chunks, then 64 x v_fma_mix_f32 with
    // compile-time delta D. Element e = q+D lives in dword e>>1, half e&1;
    // op_sel_hi[1]=1 marks src1 f16, op_sel[1] picks lo/hi half.
#define BUCKET(D, NC)                                                      \
    {                                                                      \
        const int end = __builtin_amdgcn_readfirstlane(ends[(D)]);         \
        for (; pos < end; ++pos) {                                         \
            float a1  = jd.x;                                              \
            int   csh = __float_as_int(jd.y);                              \
            jd = bdata[(pos + 1) & (D_IN - 1)];    /* broadcast prefetch */ \
            const int c0 = K8 + csh;                                       \
            uint4 w[9];                                                    \
            _Pragma("unroll")                                              \
            for (int tt = 0; tt < (NC); ++tt) {                            \
                int c = c0 + tt;                                           \
                w[tt] = *(const uint4*)(p2x + (c ^ ((c >> 3) & 7)) * 8);   \
            }                                                              \
            const unsigned* wd = (const unsigned*)w;                       \
            _Pragma("unroll")                                              \
            for (int q = 0; q < 64; ++q) {                                 \
                const int e = q + (D);                                     \
                unsigned dwv = wd[e >> 1];                                 \
                if (e & 1) {                                               \
                    asm("v_fma_mix_f32 %0, %1, %2, %0 op_sel:[0,1,0] op_sel_hi:[0,1,0]" \
                        : "+v"(zacc[q]) : "v"(a1), "v"(dwv));              \
                } else {                                                   \
                    asm("v_fma_mix_f32 %0, %1, %2, %0 op_sel:[0,0,0] op_sel_hi:[0,1,0]" \
                        : "+v"(zacc[q]) : "v"(a1), "v"(dwv));              \
                }                                                          \
            }                                                              \
        }                                                                  \
    }

    float2 jd = bdata[0];
    int pos = 0;
    BUCKET(0, 8)
    BUCKET(1, 9)
    BUCKET(2, 9)
    BUCKET(3, 9)
    BUCKET(4, 9)
    BUCKET(5, 9)
    BUCKET(6, 9)
    BUCKET(7, 9)
#undef BUCKET

    // --- store bf16 z, masking wave overlap (all bounds % 8 == 0) ---
    const int klim = wave * 4000 + 4000;
#pragma unroll
    for (int g = 0; g < 8; ++g) {
        int kg = k0 + g * 8;
        if (kg < klim) {
            bf16x8 o;
#pragma unroll
            for (int e = 0; e < 8; ++e) o[e] = (__bf16)zacc[g * 8 + e];
            *(bf16x8*)(zb + (size_t)b * D_MCB + kg) = o;
        }
    }
}

// ---------------------------------------------------------------------------
// Kernel 1.5: W fp32 -> bf16 pre-convert (one pass).
// ---------------------------------------------------------------------------
__global__ __launch_bounds__(256) void wconv_kernel(
    const float* __restrict__ W, __bf16* __restrict__ Wb)
{
    size_t i = ((size_t)blockIdx.x * 256 + threadIdx.x) * 4;
    f32x4 w = *(const f32x4*)(W + i);
    bf16x4 o;
#pragma unroll
    for (int q = 0; q < 4; ++q) o[q] = (__bf16)w[q];
    *(bf16x4*)(Wb + i) = o;
}

// ---------------------------------------------------------------------------
// Kernel 2: LDS-staged bf16 GEMM (R6 shape, kept: ~100us better than R5).
// BM=64 x BN=128, BK=64, grid = 192 1D XCD-swizzled (8 m-blocks sharing a
// Wb panel land on one XCD -> panel K-slices served by L2). 4 waves (2Mx2N),
// double-buffered LDS (48 KB), global_load_lds width=16, XOR chunk swizzle
// phys = c ^ (row&7). out = relu(z @ Wb^T + bias).
// ---------------------------------------------------------------------------
__global__ __launch_bounds__(256) void mcb_gemm_tiled_kernel(
    const __bf16* __restrict__ zbm, const __bf16* __restrict__ Wb,
    const float* __restrict__ bias, float* __restrict__ out)
{
    __shared__ __align__(16) char tile[49152];

    const int t    = threadIdx.x;
    const int lane = t & 63;
    const int wave = t >> 6;
    const int llo  = lane & 15;
    const int lhi  = lane >> 4;
    const int wm   = wave >> 1;            // 0..1 : M strip of 32
    const int wn   = wave & 1;             // 0..1 : N strip of 64

    // XCD swizzle decode: f = r + 8*(y + 8*a); x = 8a + r (n-block), y (m-block).
    const int f  = blockIdx.x;
    const int r  = f & 7;
    const int g  = f >> 3;
    const int yb = g & 7;
    const int xb = (g >> 3) * 8 + r;

    const int m0 = yb * 64;
    const int n0 = xb * 128;

    // --- staging: linear LDS dest, inverse-swizzled global source ---
    const __bf16* asrc[2];
    const __bf16* bsrc[4];
    int aoff[2], boff[4];
#pragma unroll
    for (int p = 0; p < 2; ++p) {
        int fb    = (p * 256 + t) * 16;    // byte offset in 8 KB A tile
        int row   = fb >> 7;               // 0..63 (128 B per row = 64 bf16)
        int physc = (fb >> 4) & 7;
        int logc  = physc ^ (row & 7);
        asrc[p] = zbm + (size_t)(m0 + row) * D_MCB + logc * 8;
        aoff[p] = fb;
    }
#pragma unroll
    for (int p = 0; p < 4; ++p) {
        int fb    = (p * 256 + t) * 16;    // byte offset in 16 KB B tile
        int row   = fb >> 7;               // 0..127
        int wrow  = n0 + row;
        if (wrow > N_OUT - 1) wrow = N_OUT - 1;   // clamp pad rows (masked at store)
        int physc = (fb >> 4) & 7;
        int logc  = physc ^ (row & 7);
        bsrc[p] = Wb + (size_t)wrow * D_MCB + logc * 8;
        boff[p] = 8192 + fb;
    }

#define STAGE(bufsel, kt)                                                  \
    {                                                                      \
        const int bo_ = (bufsel) * 24576;                                  \
        const int ke_ = (kt) * 64;                                         \
        _Pragma("unroll")                                                  \
        for (int p = 0; p < 2; ++p) gload16(asrc[p] + ke_, tile + bo_ + aoff[p]); \
        _Pragma("unroll")                                                  \
        for (int p = 0; p < 4; ++p) gload16(bsrc[p] + ke_, tile + bo_ + boff[p]); \
    }

    // --- fragment read offsets (swizzled) ---
    int ard[2][2], brd[4][2];
#pragma unroll
    for (int am = 0; am < 2; ++am)
#pragma unroll
        for (int ks = 0; ks < 2; ++ks) {
            int row = wm * 32 + am * 16 + llo;
            int c   = lhi + ks * 4;
            ard[am][ks] = row * 128 + (c ^ (row & 7)) * 16;
        }
#pragma unroll
    for (int bn = 0; bn < 4; ++bn)
#pragma unroll
        for (int ks = 0; ks < 2; ++ks) {
            int row = wn * 64 + bn * 16 + llo;
            int c   = lhi + ks * 4;
            brd[bn][ks] = 8192 + row * 128 + (c ^ (row & 7)) * 16;
        }

    f32x4 acc[2][4] = {};

    STAGE(0, 0);
    __syncthreads();

    int buf = 0;
    for (int kt = 0; kt < 250; ++kt) {
        if (kt + 1 < 250) STAGE(buf ^ 1, kt + 1);

        const char* base = tile + buf * 24576;
        bf16x8 a[2][2], bfr[4][2];
#pragma unroll
        for (int am = 0; am < 2; ++am)
#pragma unroll
            for (int ks = 0; ks < 2; ++ks)
                a[am][ks] = *(const bf16x8*)(base + ard[am][ks]);
#pragma unroll
        for (int bn = 0; bn < 4; ++bn)
#pragma unroll
            for (int ks = 0; ks < 2; ++ks)
                bfr[bn][ks] = *(const bf16x8*)(base + brd[bn][ks]);

#pragma unroll
        for (int ks = 0; ks < 2; ++ks)
#pragma unroll
            for (int am = 0; am < 2; ++am)
#pragma unroll
                for (int bn = 0; bn < 4; ++bn)
                    acc[am][bn] = __builtin_amdgcn_mfma_f32_16x16x32_bf16(
                        a[am][ks], bfr[bn][ks], acc[am][bn], 0, 0, 0);

        __syncthreads();
        buf ^= 1;
    }
#undef STAGE

    // --- epilogue: C/D layout col=lane&15, row=(lane>>4)*4+r ---
#pragma unroll
    for (int bn = 0; bn < 4; ++bn) {
        int col = n0 + wn * 64 + bn * 16 + llo;
        if (col < N_OUT) {
            float bv = bias[col];
#pragma unroll
            for (int am = 0; am < 2; ++am) {
                int rbase = m0 + wm * 32 + am * 16 + lhi * 4;
#pragma unroll
                for (int rr = 0; rr < 4; ++rr) {
                    float v = acc[am][bn][rr] + bv;
                    out[(size_t)(rbase + rr) * N_OUT + col] = v > 0.0f ? v : 0.0f;
                }
            }
        }
    }
}

// ---------------------------------------------------------------------------
// Kernel 2 (fallback): W stays fp32, converted in-register (no workspace).
// ---------------------------------------------------------------------------
__global__ __launch_bounds__(256) void mcb_gemm_f32_kernel(
    const __bf16* __restrict__ zbm, const float* __restrict__ W,
    const float* __restrict__ bias, float* __restrict__ out)
{
    const int lane = threadIdx.x & 63;
    const int wave = threadIdx.x >> 6;
    const int wm = wave >> 1;
    const int wn = wave & 1;
    const int llo = lane & 15;
    const int lhi = lane >> 4;

    const int m0 = blockIdx.y * 64 + wm * 32;
    const int n0 = blockIdx.x * 64 + wn * 32;

    f32x4 acc[2][2] = {};

    const int arow0 = m0 + llo;
    const int bcol0 = n0 + llo;
    const int kk = lhi * 8;

    const __bf16* aptr0 = zbm + (size_t)arow0 * D_MCB + kk;
    const __bf16* aptr1 = aptr0 + (size_t)16 * D_MCB;
    const float*  bptr0 = W + (size_t)bcol0 * D_MCB + kk;
    const float*  bptr1 = bptr0 + (size_t)16 * D_MCB;
    const bool bok0 = (bcol0 < N_OUT);
    const bool bok1 = (bcol0 + 16 < N_OUT);

    for (int k = 0; k < D_MCB; k += 32) {
        bf16x8 a0 = *(const bf16x8*)(aptr0 + k);
        bf16x8 a1 = *(const bf16x8*)(aptr1 + k);

        bf16x8 b0 = {}, b1 = {};
        if (bok0) {
            f32x4 w0 = *(const f32x4*)(bptr0 + k);
            f32x4 w1 = *(const f32x4*)(bptr0 + k + 4);
#pragma unroll
            for (int q = 0; q < 4; ++q) { b0[q] = (__bf16)w0[q]; b0[q + 4] = (__bf16)w1[q]; }
        }
        if (bok1) {
            f32x4 w0 = *(const f32x4*)(bptr1 + k);
            f32x4 w1 = *(const f32x4*)(bptr1 + k + 4);
#pragma unroll
            for (int q = 0; q < 4; ++q) { b1[q] = (__bf16)w0[q]; b1[q + 4] = (__bf16)w1[q]; }
        }

        acc[0][0] = __builtin_amdgcn_mfma_f32_16x16x32_bf16(a0, b0, acc[0][0], 0, 0, 0);
        acc[0][1] = __builtin_amdgcn_mfma_f32_16x16x32_bf16(a0, b1, acc[0][1], 0, 0, 0);
        acc[1][0] = __builtin_amdgcn_mfma_f32_16x16x32_bf16(a1, b0, acc[1][0], 0, 0, 0);
        acc[1][1] = __builtin_amdgcn_mfma_f32_16x16x32_bf16(a1, b1, acc[1][1], 0, 0, 0);
    }

#pragma unroll
    for (int bn = 0; bn < 2; ++bn) {
        int col = bcol0 + bn * 16;
        if (col >= N_OUT) continue;
        float bv = bias[col];
#pragma unroll
        for (int am = 0; am < 2; ++am) {
            int rbase = m0 + am * 16 + lhi * 4;
#pragma unroll
            for (int rr = 0; rr < 4; ++rr) {
                float v = acc[am][bn][rr] + bv;
                out[(size_t)(rbase + rr) * N_OUT + col] = v > 0.0f ? v : 0.0f;
            }
        }
    }
}

extern "C" void kernel_launch(void* const* d_in, const int* in_sizes, int n_in,
                              void* d_out, int out_size, void* d_ws, size_t ws_size,
                              hipStream_t stream) {
    // setup_inputs() order: x0, x1, s1, s2, W, b, h1, h2
    const float* x0   = (const float*)d_in[0];
    const float* x1   = (const float*)d_in[1];
    const float* s1   = (const float*)d_in[2];
    const float* s2   = (const float*)d_in[3];
    const float* W    = (const float*)d_in[4];
    const float* bias = (const float*)d_in[5];
    const int*   h1   = (const int*)d_in[6];
    const int*   h2   = (const int*)d_in[7];
    float* out = (float*)d_out;

    const size_t zb_bytes = (size_t)BATCH * D_MCB * sizeof(__bf16);   // 16,384,000
    const size_t wb_bytes = (size_t)N_OUT * D_MCB * sizeof(__bf16);   // 96,000,000

    __bf16* zbm = (__bf16*)d_ws;

    mcb_conv_kernel<<<BATCH, 256, 0, stream>>>(x0, x1, s1, s2, h1, h2, zbm);

    if (ws_size >= zb_bytes + wb_bytes) {
        __bf16* Wb = (__bf16*)((char*)d_ws + zb_bytes);
        wconv_kernel<<<46875, 256, 0, stream>>>(W, Wb);
        mcb_gemm_tiled_kernel<<<192, 256, 0, stream>>>(zbm, Wb, bias, out);
    } else {
        mcb_gemm_f32_kernel<<<dim3(47, 8), 256, 0, stream>>>(zbm, W, bias, out);
    }
}